// Round 16
// baseline (932.400 us; speedup 1.0000x reference)
//
#include <hip/hip_runtime.h>
#include <hip/hip_fp16.h>
#include <hip/hip_cooperative_groups.h>

namespace cg = cooperative_groups;

#define Bv 64
#define Gv 4096
#define Cv 32
#define Sv 16
#define NSTEP 4
#define LOG2E 1.4426950408889634f
#define LN2   0.6931471805599453f
#define GAMMA 0.01f
#define RLOG2E_G 144.26950408889634f        // LOG2E / GAMMA
#define SHIFT    72.0f                       // fixed LSE shift
#define UNSHIFT  0.4990659758388636f         // GAMMA * LN2 * 72

// raw HW transcendentals (v_exp_f32 / v_log_f32, base-2). exp2 arg in [-72, 72.3]
// -> no over/underflow; log2 arg > 0 always (sum >= 16*2^-72).
#define EXP2R(x) __builtin_amdgcn_exp2f(x)
#define LOG2R(x) __builtin_amdgcn_logf(x)

struct __align__(16) h8 { __half2 h[4]; };   // 8 fp16, one dwordx4
struct __align__(16) f8 { float4 a, b; };    // 8 f32

__device__ __forceinline__ float wave_max(float v) {
#pragma unroll
    for (int off = 32; off > 0; off >>= 1)
        v = fmaxf(v, __shfl_xor(v, off, 64));
    return v;
}

// ---- one-time: I [c][g][s] int4 -> packed pre-scaled byte offsets ----
// IT layout: [c][gc 0..63][s 0..15][lane 0..63] uint2, fields = idx*16 (16-bit).
__global__ __launch_bounds__(256) void k_itrans(const int4* __restrict__ I4,
                                                uint2* __restrict__ IT) {
    __shared__ int4 lds[64 * 17];
    int blk = blockIdx.x;                 // 32 c * 64 gc
    int c = blk >> 6, gc = blk & 63;
    size_t base = ((size_t)c * Gv + gc * 64) * Sv;   // int4 elems, [g][s] order
#pragma unroll
    for (int i = 0; i < 4; ++i) {
        int e = threadIdx.x + i * 256;    // e = gi*16 + s
        int4 ii = I4[base + e];
        lds[(e >> 4) * 17 + (e & 15)] = ii;
    }
    __syncthreads();
    size_t obase = (size_t)(c * 64 + gc) * 1024;
#pragma unroll
    for (int i = 0; i < 4; ++i) {
        int o = threadIdx.x + i * 256;    // o = s*64 + gi
        int4 ii = lds[(o & 63) * 17 + (o >> 6)];
        uint2 p;
        p.x = ((unsigned)ii.x << 4) | ((unsigned)ii.y << 20);
        p.y = ((unsigned)ii.z << 4) | ((unsigned)ii.w << 20);
        IT[obase + o] = p;
    }
}

// x [B,G] -> Lraw0 (f32) OCT-MAJOR: f8 index = oct*Gv + g  (oct = b>>3)
__global__ __launch_bounds__(256) void k_transpose(const float* __restrict__ x,
                                                   f8* __restrict__ L8) {
    __shared__ float tile[64][65];
    int g0 = blockIdx.x * 64;
#pragma unroll
    for (int i = 0; i < 16; ++i) {
        int t = threadIdx.x + i * 256;
        int b = t >> 6, gi = t & 63;
        tile[gi][b] = x[b * Gv + g0 + gi];
    }
    __syncthreads();
#pragma unroll
    for (int e = 0; e < 2; ++e) {
        int idx = threadIdx.x + e * 256;  // 512 = 64 gi * 8 oct
        int gi = idx & 63, oct = idx >> 6;
        f8 fv;
        fv.a = make_float4(tile[gi][oct * 8 + 0], tile[gi][oct * 8 + 1],
                           tile[gi][oct * 8 + 2], tile[gi][oct * 8 + 3]);
        fv.b = make_float4(tile[gi][oct * 8 + 4], tile[gi][oct * 8 + 5],
                           tile[gi][oct * 8 + 6], tile[gi][oct * 8 + 7]);
        L8[oct * Gv + g0 + gi] = fv;
    }
}

// ---- shared clause-phase body (device function) ----
__device__ __forceinline__ float clause_body(const char* tb, const uint2* Ig,
                                             h8* Csh8, size_t csIdx) {
    float sum[8];
#pragma unroll
    for (int e = 0; e < 8; ++e) sum[e] = 0.0f;
#pragma unroll
    for (int s = 0; s < Sv; ++s) {
        uint2 u = Ig[s * 64];
        unsigned a0 = u.x & 0xFFFFu, a1 = u.x >> 16;
        unsigned a2 = u.y & 0xFFFFu, a3 = u.y >> 16;
        h8 A = *(const h8*)(tb + a0);
        h8 B = *(const h8*)(tb + a1);
        h8 E = *(const h8*)(tb + a2);
        h8 D = *(const h8*)(tb + a3);
#pragma unroll
        for (int j = 0; j < 4; ++j) {
            __half2 q = __hmul2(__hmul2(A.h[j], B.h[j]), __hmul2(E.h[j], D.h[j]));
            sum[2 * j]     += EXP2R(fmaf(__low2float(q),  RLOG2E_G, -SHIFT));
            sum[2 * j + 1] += EXP2R(fmaf(__high2float(q), RLOG2E_G, -SHIFT));
        }
    }
    float ls[8];
#pragma unroll
    for (int e = 0; e < 8; ++e)
        ls[e] = fmaf(GAMMA * LN2, LOG2R(sum[e]), UNSHIFT);
    h8 outv;
#pragma unroll
    for (int j = 0; j < 4; ++j)
        outv.h[j] = __floats2half2_rn(ls[2 * j], ls[2 * j + 1]);
    Csh8[csIdx] = outv;
    float v = ls[0];
#pragma unroll
    for (int e = 1; e < 8; ++e) v = fmaxf(v, ls[e]);
    return v;
}

// ======== cooperative fused kernel: 256 blocks x 1024 threads ========
// Safe capacity: valid even at 1 block/CU. Each block serves clause roles
// (c, oct, ghalf) and (c+16, oct, ghalf) -> ONE LDS staging serves both.
__global__ __attribute__((amdgpu_flat_work_group_size(1024, 1024),
                          amdgpu_waves_per_eu(8, 8)))
void k_fused(f8* __restrict__ LA, f8* __restrict__ LB, float* __restrict__ maxb,
             const uint2* __restrict__ IT, h8* __restrict__ Csh8,
             const float* __restrict__ W, float* __restrict__ out) {
    cg::grid_group grid = cg::this_grid();
    __shared__ h8 tbl[Gv];                // 64 KB
    __shared__ float smax[16];
    __shared__ float scoef[Cv];
    const __half* __restrict__ Csf = (const __half*)Csh8;
    int tid = threadIdx.x;
    int blk = blockIdx.x;                 // 256: cbase(4)|oct(3)|ghalf(1)
    int cbase = blk >> 4;                 // 0..15
    int oct   = (blk >> 1) & 7;
    int ghalf = blk & 1;
    int lane = tid & 63, wid = tid >> 6;  // wid 0..15

    float* prev = (float*)LA;
    float* curb = (float*)LB;
    const float* LmPrev = maxb + NSTEP * 64;   // zeroed -> rd = 1

    for (int step = 0; step < NSTEP; ++step) {
        float* Mc = maxb + step * 64;
        float* Lm = Mc + 32;

        // ======== clause phase: stage once, run 2 c-roles ========
        float rd = 1.0f / fmaxf(LmPrev[0], 1.0f);
        const f8* __restrict__ src = (const f8*)prev + (size_t)oct * Gv;
#pragma unroll
        for (int i = 0; i < 4; ++i) {
            f8 v = src[tid + i * 1024];
            h8 hv;
            hv.h[0] = __floats2half2_rn(v.a.x * rd, v.a.y * rd);
            hv.h[1] = __floats2half2_rn(v.a.z * rd, v.a.w * rd);
            hv.h[2] = __floats2half2_rn(v.b.x * rd, v.b.y * rd);
            hv.h[3] = __floats2half2_rn(v.b.z * rd, v.b.w * rd);
            tbl[tid + i * 1024] = hv;
        }
        __syncthreads();
        const char* tb = (const char*)tbl;

#pragma unroll
        for (int ci = 0; ci < 2; ++ci) {
            int c = cbase + ci * 16;
            float vmax = 0.0f;
#pragma unroll
            for (int iter = 0; iter < 2; ++iter) {
                int gc = ghalf * 32 + wid * 2 + iter;
                const uint2* Ig = IT + (size_t)(c * 64 + gc) * 1024 + lane;
                size_t csIdx = ((size_t)c * 8 + oct) * Gv + gc * 64 + lane;
                vmax = fmaxf(vmax, clause_body(tb, Ig, Csh8, csIdx));
            }
            vmax = wave_max(vmax);
            if (lane == 0) smax[wid] = vmax;
            __syncthreads();
            if (tid == 0) {
                float m = smax[0];
#pragma unroll
                for (int i = 1; i < 16; ++i) m = fmaxf(m, smax[i]);
                atomicMax((int*)(Mc + c), __float_as_int(m));
            }
            __syncthreads();
        }
        grid.sync();

        // ======== combine+update phase (hden == 1; deferred norm) ========
        if (tid < Cv) {
            int cc = tid;
            float e = EXP2R(W[cc] * LOG2E);
            float wsum = e;
#pragma unroll
            for (int off = 16; off > 0; off >>= 1)
                wsum += __shfl_xor(wsum, off, 64);   // stays within lanes 0..31
            scoef[cc] = e / (wsum * fmaxf(Mc[cc], 1.0f));
        }
        __syncthreads();

        {
            int sidx = blk * 1024 + tid;  // 0 .. B*G-1 (oct-major flat f32 idx)
            float h = 0.0f;
#pragma unroll
            for (int cc = 0; cc < Cv; ++cc)
                h = fmaf(scoef[cc],
                         __half2float(Csf[(size_t)cc * (Bv * Gv) + sidx]), h);
            float rv = prev[sidx] * rd;
            float mx = fmaxf(rv, h), mn = fminf(rv, h);
            float t  = EXP2R((mn - mx) * RLOG2E_G);
            float ls = fmaf(GAMMA * LN2, LOG2R(1.0f + t), mx);
            curb[sidx] = ls;
            float vm = wave_max(ls);
            if (lane == 0) smax[wid] = vm;
        }
        __syncthreads();
        if (tid == 0) {
            float m = smax[0];
#pragma unroll
            for (int i = 1; i < 16; ++i) m = fmaxf(m, smax[i]);
            atomicMax((int*)Lm, __float_as_int(m));
        }
        grid.sync();

        LmPrev = Lm;
        float* tsw = prev; prev = curb; curb = tsw;
    }

    // ======== final output: out[b][g] = prev/max(Lm,1), de-oct-major ========
    {
        int sidx = blk * 1024 + tid;
        float d = fmaxf(LmPrev[0], 1.0f);
        float v = prev[sidx] / d;
        int oc = sidx >> 15;
        int g  = (sidx >> 3) & (Gv - 1);
        int k  = sidx & 7;
        out[(oc * 8 + k) * Gv + g] = v;
    }
}

// ======== fallback path (r13-proven separate kernels) ========
__global__ __attribute__((amdgpu_flat_work_group_size(1024, 1024),
                          amdgpu_waves_per_eu(8, 8)))
void k_clauses(const f8* __restrict__ Lprev, const float* __restrict__ LmPrev,
               const uint2* __restrict__ IT, h8* __restrict__ Csh8,
               float* __restrict__ Mc) {
    __shared__ h8 tbl[Gv];
    __shared__ float smax[16];
    int tid = threadIdx.x;
    int blk = blockIdx.x;                 // 512: c(5)|oct(3)|ghalf(1)
    int c    = blk >> 4;
    int oct  = (blk >> 1) & 7;
    int ghalf = blk & 1;

    float rd = 1.0f / fmaxf(LmPrev[0], 1.0f);
    const f8* __restrict__ src = Lprev + (size_t)oct * Gv;
#pragma unroll
    for (int i = 0; i < 4; ++i) {
        f8 v = src[tid + i * 1024];
        h8 hv;
        hv.h[0] = __floats2half2_rn(v.a.x * rd, v.a.y * rd);
        hv.h[1] = __floats2half2_rn(v.a.z * rd, v.a.w * rd);
        hv.h[2] = __floats2half2_rn(v.b.x * rd, v.b.y * rd);
        hv.h[3] = __floats2half2_rn(v.b.z * rd, v.b.w * rd);
        tbl[tid + i * 1024] = hv;
    }
    __syncthreads();

    int lane = tid & 63, wid = tid >> 6;
    const char* tb = (const char*)tbl;
    float vmax = 0.0f;
#pragma unroll
    for (int iter = 0; iter < 2; ++iter) {
        int gc = ghalf * 32 + wid * 2 + iter;
        const uint2* Ig = IT + (size_t)(c * 64 + gc) * 1024 + lane;
        size_t csIdx = ((size_t)c * 8 + oct) * Gv + gc * 64 + lane;
        vmax = fmaxf(vmax, clause_body(tb, Ig, Csh8, csIdx));
    }
    vmax = wave_max(vmax);
    if (lane == 0) smax[wid] = vmax;
    __syncthreads();
    if (tid == 0) {
        float m = smax[0];
#pragma unroll
        for (int i = 1; i < 16; ++i) m = fmaxf(m, smax[i]);
        atomicMax((int*)(Mc + c), __float_as_int(m));
    }
}

__global__ __launch_bounds__(256) void k_combupd(const h8* __restrict__ Csh8,
                                                 const float* __restrict__ W,
                                                 const float* __restrict__ Mc,
                                                 const f8* __restrict__ Lprev,
                                                 const float* __restrict__ LmPrev,
                                                 f8* __restrict__ Lout,
                                                 float* __restrict__ LmOut) {
    __shared__ float smax[4];
    __shared__ float scoef[Cv];
    if (threadIdx.x < Cv) {
        int c = threadIdx.x;
        float e = EXP2R(W[c] * LOG2E);
        float wsum = e;
#pragma unroll
        for (int off = 16; off > 0; off >>= 1)
            wsum += __shfl_xor(wsum, off, 64);
        scoef[c] = e / (wsum * fmaxf(Mc[c], 1.0f));
    }
    __syncthreads();

    int tid = blockIdx.x * 256 + threadIdx.x;
    float h[8];
#pragma unroll
    for (int e = 0; e < 8; ++e) h[e] = 0.0f;
#pragma unroll
    for (int c = 0; c < Cv; ++c) {
        float w = scoef[c];
        h8 v = Csh8[(size_t)c * (Gv * 8) + tid];
#pragma unroll
        for (int j = 0; j < 4; ++j) {
            h[2 * j]     = fmaf(w, __low2float(v.h[j]),  h[2 * j]);
            h[2 * j + 1] = fmaf(w, __high2float(v.h[j]), h[2 * j + 1]);
        }
    }

    float rd = 1.0f / fmaxf(LmPrev[0], 1.0f);
    f8 r = Lprev[tid];
    const float* rp = &r.a.x;
    f8 outv;
    float* op = &outv.a.x;
    float vmax = 0.0f;
#pragma unroll
    for (int e = 0; e < 8; ++e) {
        float hn = h[e];
        float rv = rp[e] * rd;
        float mx = fmaxf(rv, hn), mn = fminf(rv, hn);
        float t  = EXP2R((mn - mx) * RLOG2E_G);
        float ls = fmaf(GAMMA * LN2, LOG2R(1.0f + t), mx);
        op[e] = ls;
        vmax = fmaxf(vmax, ls);
    }
    Lout[tid] = outv;
    vmax = wave_max(vmax);
    int lane = threadIdx.x & 63, wid = threadIdx.x >> 6;
    if (lane == 0) smax[wid] = vmax;
    __syncthreads();
    if (threadIdx.x == 0) {
        float m = fmaxf(fmaxf(smax[0], smax[1]), fmaxf(smax[2], smax[3]));
        atomicMax((int*)LmOut, __float_as_int(m));
    }
}

__global__ __launch_bounds__(256) void k_out(const float4* __restrict__ Lraw4,
                                             const float* __restrict__ Lm,
                                             float* __restrict__ out) {
    int tid = blockIdx.x * 256 + threadIdx.x;
    float d = fmaxf(Lm[0], 1.0f);
    float4 lv = Lraw4[tid];
    int lin = tid * 4;
    int oct = lin >> 15;
    int g   = (lin >> 3) & (Gv - 1);
    int k0  = lin & 7;
    int b   = oct * 8 + k0;
    out[(b + 0) * Gv + g] = lv.x / d;
    out[(b + 1) * Gv + g] = lv.y / d;
    out[(b + 2) * Gv + g] = lv.z / d;
    out[(b + 3) * Gv + g] = lv.w / d;
}

extern "C" void kernel_launch(void* const* d_in, const int* in_sizes, int n_in,
                              void* d_out, int out_size, void* d_ws, size_t ws_size,
                              hipStream_t stream) {
    const float* x = (const float*)d_in[0];   // [64, 4096]
    const float* W = (const float*)d_in[1];   // [1, 32]
    const int*   I = (const int*)d_in[2];     // [32, 4096, 16, 4]
    float* out = (float*)d_out;               // [64, 4096]

    float*  ws    = (float*)d_ws;
    f8*     LrawA = (f8*)ws;                   // 262144 f32, oct-major
    f8*     LrawB = (f8*)(ws + 262144);        // 262144 f32, oct-major
    float*  maxb  = ws + 524288;               // NSTEP*64 + 64 atomic slots
    h8*     Csh   = (h8*)(ws + 1048576);       // 8388608 fp16 (16 MB)
    uint2*  ITp   = (uint2*)(ws + 5242880);    // 2097152 uint2 (16 MB)

    (void)hipMemsetAsync(maxb, 0, (NSTEP * 64 + 64) * sizeof(float), stream);
    k_itrans   <<<Cv * 64, 256, 0, stream>>>((const int4*)I, ITp);
    k_transpose<<<Gv / 64, 256, 0, stream>>>(x, LrawA);

    void* args[] = { (void*)&LrawA, (void*)&LrawB, (void*)&maxb,
                     (void*)&ITp, (void*)&Csh, (void*)&W, (void*)&out };
    hipError_t err = hipLaunchCooperativeKernel((const void*)k_fused, dim3(256),
                                                dim3(1024), args, 0, stream);
    if (err != hipSuccess) {
        // fallback: proven r13 multi-kernel path (identical math)
        const float* LmPrev = maxb + NSTEP * 64;
        f8* prev = LrawA;
        f8* cur  = LrawB;
        for (int step = 0; step < NSTEP; ++step) {
            float* Mc = maxb + step * 64;
            float* Lm = Mc + 32;
            k_clauses<<<512, 1024, 0, stream>>>(prev, LmPrev, (const uint2*)ITp,
                                                Csh, Mc);
            k_combupd<<<(Bv * Gv) / 2048, 256, 0, stream>>>(Csh, W, Mc, prev,
                                                            LmPrev, cur, Lm);
            LmPrev = Lm;
            f8* t = prev; prev = cur; cur = t;
        }
        k_out<<<(Bv * Gv) / 1024, 256, 0, stream>>>((const float4*)prev, LmPrev,
                                                    out);
    }
}

// Round 17
// 169.551 us; speedup vs baseline: 5.4992x; 5.4992x over previous
//
#include <hip/hip_runtime.h>
#include <hip/hip_fp16.h>

#define Bv 64
#define Gv 4096
#define Cv 32
#define Sv 16
#define NSTEP 4
#define LOG2E 1.4426950408889634f
#define LN2   0.6931471805599453f
#define GAMMA 0.01f
#define RLOG2E_G 144.26950408889634f        // LOG2E / GAMMA
#define SHIFT    72.0f                       // fixed LSE shift
#define UNSHIFT  0.4990659758388636f         // GAMMA * LN2 * 72

// raw HW transcendentals (v_exp_f32 / v_log_f32, base-2). exp2 arg in [-72, 72.3]
// -> no over/underflow; log2 arg > 0 always (sum >= 16*2^-72).
#define EXP2R(x) __builtin_amdgcn_exp2f(x)
#define LOG2R(x) __builtin_amdgcn_logf(x)

struct __align__(16) h8 { __half2 h[4]; };   // 8 fp16, one dwordx4
struct __align__(16) f8 { float4 a, b; };    // 8 f32

__device__ __forceinline__ float wave_max(float v) {
#pragma unroll
    for (int off = 32; off > 0; off >>= 1)
        v = fmaxf(v, __shfl_xor(v, off, 64));
    return v;
}

// ---- one-time setup, single dispatch ----
// blocks 0..2047: I [c][g][s] int4 -> IT [c][gc][s][lane] uint2 packed
//   pre-scaled byte offsets (fields = idx*16, 16-bit).
// blocks 2048..2111: x [B,G] -> Lraw0 (f32) OCT-MAJOR (f8 idx = oct*Gv+g).
__global__ __launch_bounds__(256) void k_setup(const int4* __restrict__ I4,
                                               uint2* __restrict__ IT,
                                               const float* __restrict__ x,
                                               f8* __restrict__ L8) {
    if (blockIdx.x < 2048) {
        __shared__ int4 lds[64 * 17];
        int blk = blockIdx.x;                 // 32 c * 64 gc
        int c = blk >> 6, gc = blk & 63;
        size_t base = ((size_t)c * Gv + gc * 64) * Sv;   // int4, [g][s] order
#pragma unroll
        for (int i = 0; i < 4; ++i) {
            int e = threadIdx.x + i * 256;    // e = gi*16 + s
            int4 ii = I4[base + e];
            lds[(e >> 4) * 17 + (e & 15)] = ii;
        }
        __syncthreads();
        size_t obase = (size_t)(c * 64 + gc) * 1024;
#pragma unroll
        for (int i = 0; i < 4; ++i) {
            int o = threadIdx.x + i * 256;    // o = s*64 + gi
            int4 ii = lds[(o & 63) * 17 + (o >> 6)];
            uint2 p;
            p.x = ((unsigned)ii.x << 4) | ((unsigned)ii.y << 20);
            p.y = ((unsigned)ii.z << 4) | ((unsigned)ii.w << 20);
            IT[obase + o] = p;
        }
    } else {
        __shared__ float tile[64][65];
        int g0 = (blockIdx.x - 2048) * 64;
#pragma unroll
        for (int i = 0; i < 16; ++i) {
            int t = threadIdx.x + i * 256;
            int b = t >> 6, gi = t & 63;
            tile[gi][b] = x[b * Gv + g0 + gi];
        }
        __syncthreads();
#pragma unroll
        for (int e = 0; e < 2; ++e) {
            int idx = threadIdx.x + e * 256;  // 512 = 64 gi * 8 oct
            int gi = idx & 63, oct = idx >> 6;
            f8 fv;
            fv.a = make_float4(tile[gi][oct * 8 + 0], tile[gi][oct * 8 + 1],
                               tile[gi][oct * 8 + 2], tile[gi][oct * 8 + 3]);
            fv.b = make_float4(tile[gi][oct * 8 + 4], tile[gi][oct * 8 + 5],
                               tile[gi][oct * 8 + 6], tile[gi][oct * 8 + 7]);
            L8[oct * Gv + g0 + gi] = fv;
        }
    }
}

// block = (c, oct, ghalf), 1024 threads (16 waves x 2 gc-iters), 8 waves/SIMD.
// Stages full-G 8-batch slice of R = Lprev/max(LmPrev,1) into LDS as fp16;
// all S*L gathers hit LDS (ds_read_b128, pre-scaled packed offsets).
__global__ __attribute__((amdgpu_flat_work_group_size(1024, 1024),
                          amdgpu_waves_per_eu(8, 8)))
void k_clauses(const f8* __restrict__ Lprev, const float* __restrict__ LmPrev,
               const uint2* __restrict__ IT, h8* __restrict__ Csh8,
               float* __restrict__ Mc) {
    __shared__ h8 tbl[Gv];                // 64 KB
    __shared__ float smax[16];
    int tid = threadIdx.x;
    int blk = blockIdx.x;                 // 512: c(5)|oct(3)|ghalf(1)
    int c    = blk >> 4;
    int oct  = (blk >> 1) & 7;
    int ghalf = blk & 1;

    float rd = 1.0f / fmaxf(LmPrev[0], 1.0f);
    const f8* __restrict__ src = Lprev + (size_t)oct * Gv;
#pragma unroll
    for (int i = 0; i < 4; ++i) {
        f8 v = src[tid + i * 1024];
        h8 hv;
        hv.h[0] = __floats2half2_rn(v.a.x * rd, v.a.y * rd);
        hv.h[1] = __floats2half2_rn(v.a.z * rd, v.a.w * rd);
        hv.h[2] = __floats2half2_rn(v.b.x * rd, v.b.y * rd);
        hv.h[3] = __floats2half2_rn(v.b.z * rd, v.b.w * rd);
        tbl[tid + i * 1024] = hv;
    }
    __syncthreads();

    int lane = tid & 63, wid = tid >> 6;  // wid 0..15
    const char* tb = (const char*)tbl;
    float vmax = 0.0f;

#pragma unroll
    for (int iter = 0; iter < 2; ++iter) {
        int gc = ghalf * 32 + wid * 2 + iter;
        const uint2* __restrict__ Ig = IT + (size_t)(c * 64 + gc) * 1024 + lane;

        float sum[8];
#pragma unroll
        for (int e = 0; e < 8; ++e) sum[e] = 0.0f;

#pragma unroll
        for (int s = 0; s < Sv; ++s) {
            uint2 u = Ig[s * 64];
            unsigned a0 = u.x & 0xFFFFu, a1 = u.x >> 16;
            unsigned a2 = u.y & 0xFFFFu, a3 = u.y >> 16;
            h8 A = *(const h8*)(tb + a0);
            h8 B = *(const h8*)(tb + a1);
            h8 E = *(const h8*)(tb + a2);
            h8 D = *(const h8*)(tb + a3);
#pragma unroll
            for (int j = 0; j < 4; ++j) {
                __half2 q = __hmul2(__hmul2(A.h[j], B.h[j]), __hmul2(E.h[j], D.h[j]));
                sum[2 * j]     += EXP2R(fmaf(__low2float(q),  RLOG2E_G, -SHIFT));
                sum[2 * j + 1] += EXP2R(fmaf(__high2float(q), RLOG2E_G, -SHIFT));
            }
        }

        float ls[8];
#pragma unroll
        for (int e = 0; e < 8; ++e)
            ls[e] = fmaf(GAMMA * LN2, LOG2R(sum[e]), UNSHIFT);

        h8 outv;
#pragma unroll
        for (int j = 0; j < 4; ++j)
            outv.h[j] = __floats2half2_rn(ls[2 * j], ls[2 * j + 1]);
        Csh8[((size_t)c * 8 + oct) * Gv + gc * 64 + lane] = outv;

#pragma unroll
        for (int e = 0; e < 8; ++e) vmax = fmaxf(vmax, ls[e]);
    }

    vmax = wave_max(vmax);
    if (lane == 0) smax[wid] = vmax;
    __syncthreads();
    if (tid == 0) {
        float m = smax[0];
#pragma unroll
        for (int i = 1; i < 16; ++i) m = fmaxf(m, smax[i]);
        atomicMax((int*)(Mc + c), __float_as_int(m));   // c uniform across block
    }
}

// Fused combine+update (hden == 1: H is a convex combination of values <= 1).
// r = Lprev*1/max(LmPrev,1) inline (deferred normalization).
// Writes UNNORMALIZED Lout + its global max LmOut.  8 elems per thread.
__global__ __launch_bounds__(256) void k_combupd(const h8* __restrict__ Csh8,
                                                 const float* __restrict__ W,
                                                 const float* __restrict__ Mc,
                                                 const f8* __restrict__ Lprev,
                                                 const float* __restrict__ LmPrev,
                                                 f8* __restrict__ Lout,
                                                 float* __restrict__ LmOut) {
    __shared__ float smax[4];
    __shared__ float scoef[Cv];
    if (threadIdx.x < Cv) {               // lanes 0..31 of wave 0
        int c = threadIdx.x;
        float e = EXP2R(W[c] * LOG2E);
        float wsum = e;
#pragma unroll
        for (int off = 16; off > 0; off >>= 1)
            wsum += __shfl_xor(wsum, off, 64);
        scoef[c] = e / (wsum * fmaxf(Mc[c], 1.0f));
    }
    __syncthreads();

    int tid = blockIdx.x * 256 + threadIdx.x;     // 0 .. B*G/8-1
    float h[8];
#pragma unroll
    for (int e = 0; e < 8; ++e) h[e] = 0.0f;
#pragma unroll
    for (int c = 0; c < Cv; ++c) {
        float w = scoef[c];
        h8 v = Csh8[(size_t)c * (Gv * 8) + tid];
#pragma unroll
        for (int j = 0; j < 4; ++j) {
            h[2 * j]     = fmaf(w, __low2float(v.h[j]),  h[2 * j]);
            h[2 * j + 1] = fmaf(w, __high2float(v.h[j]), h[2 * j + 1]);
        }
    }

    float rd = 1.0f / fmaxf(LmPrev[0], 1.0f);
    f8 r = Lprev[tid];
    const float* rp = &r.a.x;
    f8 outv;
    float* op = &outv.a.x;
    float vmax = 0.0f;
#pragma unroll
    for (int e = 0; e < 8; ++e) {
        float hn = h[e];                  // hden == 1
        float rv = rp[e] * rd;            // deferred normalization
        float mx = fmaxf(rv, hn), mn = fminf(rv, hn);
        float t  = EXP2R((mn - mx) * RLOG2E_G);
        float ls = fmaf(GAMMA * LN2, LOG2R(1.0f + t), mx);
        op[e] = ls;
        vmax = fmaxf(vmax, ls);
    }
    Lout[tid] = outv;
    vmax = wave_max(vmax);
    int lane = threadIdx.x & 63, wid = threadIdx.x >> 6;
    if (lane == 0) smax[wid] = vmax;
    __syncthreads();
    if (threadIdx.x == 0) {
        float m = fmaxf(fmaxf(smax[0], smax[1]), fmaxf(smax[2], smax[3]));
        atomicMax((int*)LmOut, __float_as_int(m));
    }
}

// Final: out[b][g] = Lraw/max(Lm,1) scattered from oct-major to [B,G].
__global__ __launch_bounds__(256) void k_out(const float4* __restrict__ Lraw4,
                                             const float* __restrict__ Lm,
                                             float* __restrict__ out) {
    int tid = blockIdx.x * 256 + threadIdx.x;     // 0 .. B*G/4-1
    float d = fmaxf(Lm[0], 1.0f);
    float4 lv = Lraw4[tid];
    int lin = tid * 4;                        // oct-major linear f32 index
    int oct = lin >> 15;
    int g   = (lin >> 3) & (Gv - 1);
    int k0  = lin & 7;                        // 0 or 4
    int b   = oct * 8 + k0;
    out[(b + 0) * Gv + g] = lv.x / d;
    out[(b + 1) * Gv + g] = lv.y / d;
    out[(b + 2) * Gv + g] = lv.z / d;
    out[(b + 3) * Gv + g] = lv.w / d;
}

extern "C" void kernel_launch(void* const* d_in, const int* in_sizes, int n_in,
                              void* d_out, int out_size, void* d_ws, size_t ws_size,
                              hipStream_t stream) {
    const float* x = (const float*)d_in[0];   // [64, 4096]
    const float* W = (const float*)d_in[1];   // [1, 32]
    const int*   I = (const int*)d_in[2];     // [32, 4096, 16, 4]
    float* out = (float*)d_out;               // [64, 4096]

    float*  ws    = (float*)d_ws;
    f8*     LrawA = (f8*)ws;                   // 262144 f32, oct-major
    f8*     LrawB = (f8*)(ws + 262144);        // 262144 f32, oct-major
    float*  maxb  = ws + 524288;               // NSTEP*64 + 64 atomic slots
    h8*     Csh   = (h8*)(ws + 1048576);       // 8388608 fp16 (16 MB)
    uint2*  ITp   = (uint2*)(ws + 5242880);    // 2097152 uint2 (16 MB)

    (void)hipMemsetAsync(maxb, 0, (NSTEP * 64 + 64) * sizeof(float), stream);
    k_setup<<<2112, 256, 0, stream>>>((const int4*)I, ITp, x, LrawA);

    const float* LmPrev = maxb + NSTEP * 64;   // zeros -> rd = 1
    f8* prev = LrawA;
    f8* cur  = LrawB;
    for (int step = 0; step < NSTEP; ++step) {
        float* Mc = maxb + step * 64;     // [32] per-clause maxima
        float* Lm = Mc + 32;
        k_clauses<<<512, 1024, 0, stream>>>(prev, LmPrev, (const uint2*)ITp,
                                            Csh, Mc);
        k_combupd<<<(Bv * Gv) / 2048, 256, 0, stream>>>(Csh, W, Mc, prev,
                                                        LmPrev, cur, Lm);
        LmPrev = Lm;
        f8* t = prev; prev = cur; cur = t;
    }
    k_out<<<(Bv * Gv) / 1024, 256, 0, stream>>>((const float4*)prev, LmPrev, out);
}